// Round 1
// baseline (127.740 us; speedup 1.0000x reference)
//
#include <hip/hip_runtime.h>

#define B_ 16
#define T_ 800
#define D_ 256
#define K_ 64

// ---------------- Kernel A: dist -> softmax(K) -> r, S = sum_t r ----------------
// grid = B * (T/32) = 400 blocks, 256 threads (4 waves; wave w owns t = w*8..w*8+7, lane = k)
__global__ __launch_bounds__(256) void kernelA(
    const float* __restrict__ x, const float* __restrict__ mu,
    const float* __restrict__ prec, float* __restrict__ r, float* __restrict__ S)
{
    __shared__ float xs[32 * 256];     // x tile, 32 KB
    __shared__ float muT[64 * 65];     // transposed mu chunk, pad 65 -> conflict-free
    __shared__ float xx[32];
    __shared__ float mm[64];
    __shared__ float p2[64];
    __shared__ float Sblk[64];

    const int tid = threadIdx.x;
    const int b  = blockIdx.x / 25;
    const int t0 = (blockIdx.x % 25) * 32;

    // stage x tile (contiguous 8192 floats)
    {
        const float4* xg4 = (const float4*)(x + (size_t)(b * T_ + t0) * D_);
        float4* xs4 = (float4*)xs;
        #pragma unroll
        for (int i = 0; i < 8; ++i) xs4[tid + i * 256] = xg4[tid + i * 256];
    }

    if (tid < 64) { float p = prec[tid]; p2[tid] = p * p; Sblk[tid] = 0.f; }

    // mm[k] = ||mu_k||^2 : 4 threads per k
    {
        const int k = tid >> 2, j = tid & 3;
        const float4* mg4 = (const float4*)(mu + (size_t)k * D_ + j * 64);
        float s = 0.f;
        #pragma unroll
        for (int i = 0; i < 16; ++i) { float4 v = mg4[i]; s += v.x*v.x + v.y*v.y + v.z*v.z + v.w*v.w; }
        s += __shfl_xor(s, 1); s += __shfl_xor(s, 2);
        if (j == 0) mm[k] = s;
    }

    __syncthreads();   // xs ready

    // xx[t] = ||x_t||^2 : 8 threads per t, from LDS
    {
        const int t = tid >> 3, j = tid & 7;
        const float4* xr4 = (const float4*)(xs + t * 256 + j * 32);
        float s = 0.f;
        #pragma unroll
        for (int i = 0; i < 8; ++i) { float4 v = xr4[i]; s += v.x*v.x + v.y*v.y + v.z*v.z + v.w*v.w; }
        s += __shfl_xor(s, 1); s += __shfl_xor(s, 2); s += __shfl_xor(s, 4);
        if (j == 0) xx[t] = s;
    }

    const int w = tid >> 6;   // wave id
    const int k = tid & 63;   // lane = component
    float acc[8];
    #pragma unroll
    for (int i = 0; i < 8; ++i) acc[i] = 0.f;

    for (int c = 0; c < 4; ++c) {
        __syncthreads();
        // stage muT chunk: muT[dd][kk] = mu[kk][c*64+dd]
        #pragma unroll
        for (int i = 0; i < 16; ++i) {
            int idx = tid + i * 256;            // 0..4095
            int kk = idx >> 6, dd = idx & 63;
            muT[dd * 65 + kk] = mu[(size_t)kk * D_ + c * 64 + dd];
        }
        __syncthreads();
        #pragma unroll
        for (int q = 0; q < 16; ++q) {
            const float m0 = muT[(q * 4 + 0) * 65 + k];
            const float m1 = muT[(q * 4 + 1) * 65 + k];
            const float m2 = muT[(q * 4 + 2) * 65 + k];
            const float m3 = muT[(q * 4 + 3) * 65 + k];
            #pragma unroll
            for (int tt = 0; tt < 8; ++tt) {
                const float4 xv = *(const float4*)&xs[(w * 8 + tt) * 256 + c * 64 + q * 4];
                acc[tt] = fmaf(xv.x, m0, acc[tt]);
                acc[tt] = fmaf(xv.y, m1, acc[tt]);
                acc[tt] = fmaf(xv.z, m2, acc[tt]);
                acc[tt] = fmaf(xv.w, m3, acc[tt]);
            }
        }
    }

    // epilogue: llk = -p^2 * (xx - 2*dot + mm) ; softmax over k (one wave)
    const float p2k = p2[k];
    const float mmk = mm[k];
    #pragma unroll
    for (int tt = 0; tt < 8; ++tt) {
        const int t = w * 8 + tt;
        float llk = p2k * (2.f * acc[tt] - xx[t] - mmk);
        float mx = llk;
        #pragma unroll
        for (int off = 32; off > 0; off >>= 1) mx = fmaxf(mx, __shfl_xor(mx, off));
        float e = __expf(llk - mx);
        float sum = e;
        #pragma unroll
        for (int off = 32; off > 0; off >>= 1) sum += __shfl_xor(sum, off);
        float rv = e / sum;
        r[(size_t)(b * T_ + t0 + t) * K_ + k] = rv;
        atomicAdd(&Sblk[k], rv);
    }
    __syncthreads();
    if (tid < 64) atomicAdd(&S[b * K_ + tid], Sblk[tid]);
}

// ---------------- Kernel B: P[b,k,d] = sum_t r[b,t,k] * x[b,t,d] (split-T) ----------------
// grid = B * 5(tchunks) * 4(ktiles) * 4(dtiles) = 1280 blocks, 256 threads
__global__ __launch_bounds__(256) void kernelB(
    const float* __restrict__ x, const float* __restrict__ r, float* __restrict__ P)
{
    __shared__ float rl[32 * 16];
    __shared__ float xsb[32 * 64];

    const int tid = threadIdx.x;
    int bid = blockIdx.x;
    const int b = bid / 80; int rem = bid % 80;
    const int tc = rem / 16; rem &= 15;
    const int k0 = (rem >> 2) * 16;
    const int d0 = (rem & 3) * 64;

    const int kk = tid >> 4;   // 0..15
    const int dq = tid & 15;   // float4 within 64-d tile

    float4 acc = {0.f, 0.f, 0.f, 0.f};

    for (int i = 0; i < 5; ++i) {
        const int t0 = tc * 160 + i * 32;
        #pragma unroll
        for (int j = 0; j < 2; ++j) {
            int idx = tid + j * 256;            // 0..511
            int t = idx >> 4, kx = idx & 15;
            rl[idx] = r[(size_t)(b * T_ + t0 + t) * K_ + k0 + kx];
        }
        {
            const float4* xg4 = (const float4*)x;
            float4* xs4 = (float4*)xsb;
            #pragma unroll
            for (int j = 0; j < 2; ++j) {
                int idx = tid + j * 256;        // 0..511 float4s
                int t = idx >> 4, d4 = idx & 15;
                xs4[idx] = xg4[(size_t)(b * T_ + t0 + t) * 64 + (d0 >> 2) + d4];
            }
        }
        __syncthreads();
        #pragma unroll 8
        for (int t = 0; t < 32; ++t) {
            float rv = rl[t * 16 + kk];
            float4 xv = ((const float4*)xsb)[t * 16 + dq];
            acc.x = fmaf(rv, xv.x, acc.x);
            acc.y = fmaf(rv, xv.y, acc.y);
            acc.z = fmaf(rv, xv.z, acc.z);
            acc.w = fmaf(rv, xv.w, acc.w);
        }
        __syncthreads();
    }

    float* Pp = P + (size_t)(b * K_ + k0 + kk) * D_ + d0 + dq * 4;
    atomicAdd(Pp + 0, acc.x);
    atomicAdd(Pp + 1, acc.y);
    atomicAdd(Pp + 2, acc.z);
    atomicAdd(Pp + 3, acc.w);
}

// ---------------- Kernel C: out = P*inv - (S*inv)*mu,  inv = 1/(S+1e-9) ----------------
// grid = 256 blocks * 256 threads, 1 float4 each (65536 float4 total)
__global__ __launch_bounds__(256) void kernelC(
    const float* __restrict__ P, const float* __restrict__ S,
    const float* __restrict__ mu, float* __restrict__ out)
{
    const int o4 = blockIdx.x * 256 + threadIdx.x;   // 0..65535
    const int d4 = o4 & 63;
    const int k  = (o4 >> 6) & 63;
    const int b  = o4 >> 12;
    const float s = S[b * K_ + k];
    const float inv = 1.f / (s + 1e-9f);
    const float sm = s * inv;
    const float4 p = ((const float4*)P)[o4];
    const float4 m = ((const float4*)mu)[k * 64 + d4];
    float4 o;
    o.x = p.x * inv - sm * m.x;
    o.y = p.y * inv - sm * m.y;
    o.z = p.z * inv - sm * m.z;
    o.w = p.w * inv - sm * m.w;
    ((float4*)out)[o4] = o;
}

extern "C" void kernel_launch(void* const* d_in, const int* in_sizes, int n_in,
                              void* d_out, int out_size, void* d_ws, size_t ws_size,
                              hipStream_t stream) {
    const float* x    = (const float*)d_in[0];
    const float* mu   = (const float*)d_in[1];
    const float* prec = (const float*)d_in[2];
    float* out = (float*)d_out;

    float* r = (float*)d_ws;                          // B*T*K   = 819200 floats
    float* P = r + (size_t)B_ * T_ * K_;              // B*K*D   = 262144 floats
    float* S = P + (size_t)B_ * K_ * D_;              // B*K     = 1024 floats

    // zero P and S (contiguous)
    hipMemsetAsync(P, 0, (size_t)(B_ * K_ * D_ + B_ * K_) * sizeof(float), stream);

    kernelA<<<400, 256, 0, stream>>>(x, mu, prec, r, S);
    kernelB<<<1280, 256, 0, stream>>>(x, r, P);
    kernelC<<<256, 256, 0, stream>>>(P, S, mu, out);
}